// Round 3
// baseline (94.650 us; speedup 1.0000x reference)
//
#include <hip/hip_runtime.h>

// ExemplarNoAttention: logits[b,c] = log( sum_{e: label[e]==c} exp(-beta*d2[b,e]) + eps )
// d2[b,e] = ||x_b||^2 + ||e_e||^2 - 2<x_b,e_e>, clamped >= 0; beta = softplus(beta_raw).
//
// Round 12 (from R11 = 94.5 us):
//  R11's fusion was ~neutral: prep's savings were eaten by the in-main fp32
//  staging (2x bytes + norm/cvt VALU), replicated 8x across the btiles sharing
//  a chunk. This round HALVES that replication: BCOLS 128 -> 256 (grid 4 x 98).
//  Each wave feeds 4 col-groups of 16 from the SAME staged A-frags:
//   - stage loads / cvt+norm VALU / LDS writes / barriers halve per output,
//   - ex staging redundancy 8x -> 4x (102 -> 51 MB of L2/L3 reads),
//   - labels preloaded ONCE per block (512 ints, single-buffer LDS) instead of
//     re-staged through the double-buffer every stage.
//  MFMA1 count and t-compute VALU are problem-fixed (unchanged). All group
//  arrays are compile-time indexed (full unroll) to stay in registers.
// Keeps: single barrier per stage, exp2 log-domain, dead-subtile skip (t<=-25
// => fp16(2^t)==0 exactly, MFMA2 provably no-op), contention-free partial
// stores + coalesced reduce. Harness floor (~41 us poison fill + restores).

#define NB      1024
#define NE      50000
#define NCHUNK  98       // 98 chunks * 512 e-rows (last chunk padded in-kernel)
#define KD      64
#define NC      10
#define SROWS   64       // e-rows per stage
#define NSTAGE  8        // 512 / NSTAGE
#define CROWS   512      // e-rows per chunk
#define LROW    72       // padded LDS row stride in halfs (144 B)
#define BCOLS   256      // batch cols per block (4 col-groups of 64 per wave-set)
#define NGRP    4        // col-groups per wave

#define LOG2E   1.4426950408889634f

using half8   = __attribute__((ext_vector_type(8))) _Float16;  // 16x16x32 A/B frag (4 VGPRs)
using half4v  = __attribute__((ext_vector_type(4))) _Float16;  // 16x16x16 A/B frag (2 VGPRs)
using floatx4 = __attribute__((ext_vector_type(4))) float;

__device__ __forceinline__ float softplus_f(float x) {
  return (x > 20.f) ? x : log1pf(__expf(x));
}

__device__ __forceinline__ float exp2_hw(float x) {
#if __has_builtin(__builtin_amdgcn_exp2f)
  return __builtin_amdgcn_exp2f(x);
#else
  return exp2f(x);
#endif
}

// ---------------------------------------------------------------------------
// main: grid (4 btiles, 98 chunks), block = 4 waves, 256 batch cols per block.
// Wave w owns cols {btile*256 + w*16 + 64g : g=0..3}. Per stage (64 e-rows):
// prefetch next stage ex fp32 global->regs; compute 4 subtiles from LDS buf b
// (shared A-frags feed all 4 col-groups); cvt+norm prefetched rows -> buf b^1;
// ONE barrier.
// Subtile: 2 MFMA1 per group -> d_g[e][b]; t = min(s2*d + cb_g + ce, 0) in
// log2-domain; if all 16 lanes' t <= -25, fp16(2^t)==0 -> skip exp/onehot/MFMA2.
// Flush: plain coalesced stores into part[chunk] -- zero atomics/contention.
// ---------------------------------------------------------------------------
__global__ __launch_bounds__(256) void main_kernel(
    const float* __restrict__ x, const float* __restrict__ ex,
    const int* __restrict__ labels, const float* __restrict__ beta_raw,
    float* __restrict__ part)
{
  __shared__ _Float16 Ah[2][SROWS * LROW];
  __shared__ float    Ce[2][SROWS];
  __shared__ int      Lb_all[CROWS];

  const int tid  = threadIdx.x;
  const int wave = tid >> 6;
  const int lane = tid & 63;
  const int l15  = lane & 15;
  const int quad = lane >> 4;

  const int btile = blockIdx.x;
  const int chunk = blockIdx.y;
  const int e0    = chunk * CROWS;
  const int bm0   = btile * BCOLS + wave * 16;  // col-group 0; group g at +64g

  const float beta = softplus_f(beta_raw[0]);
  const float nb2  = -beta * LOG2E;             // -beta*log2(e)
  const float s2   = 2.f * beta * LOG2E;

  // ---- labels for the whole chunk, once (single-buffer; covered by prologue barrier)
  #pragma unroll
  for (int i = 0; i < CROWS / 256; ++i) {
    const int r = i * 256 + tid;
    const int grow = e0 + r;
    Lb_all[r] = (grow < NE) ? labels[grow] : 0;
  }

  // ---- x B-frags + cb for 4 col-groups, from fp32 x, once per block ----
  half8 bx[NGRP][2];
  float cbl[NGRP];
  #pragma unroll
  for (int g = 0; g < NGRP; ++g) {
    const float* xr = x + (size_t)(bm0 + 64 * g + l15) * KD;
    const float4 v0 = *(const float4*)(xr + quad * 8);
    const float4 v1 = *(const float4*)(xr + quad * 8 + 4);
    const float4 v2 = *(const float4*)(xr + quad * 8 + 32);
    const float4 v3 = *(const float4*)(xr + quad * 8 + 36);
    bx[g][0] = half8{ (_Float16)v0.x, (_Float16)v0.y, (_Float16)v0.z, (_Float16)v0.w,
                      (_Float16)v1.x, (_Float16)v1.y, (_Float16)v1.z, (_Float16)v1.w };
    bx[g][1] = half8{ (_Float16)v2.x, (_Float16)v2.y, (_Float16)v2.z, (_Float16)v2.w,
                      (_Float16)v3.x, (_Float16)v3.y, (_Float16)v3.z, (_Float16)v3.w };
    float s = v0.x*v0.x + v0.y*v0.y + v0.z*v0.z + v0.w*v0.w
            + v1.x*v1.x + v1.y*v1.y + v1.z*v1.z + v1.w*v1.w
            + v2.x*v2.x + v2.y*v2.y + v2.z*v2.z + v2.w*v2.w
            + v3.x*v3.x + v3.y*v3.y + v3.z*v3.z + v3.w*v3.w;
    s += __shfl_xor(s, 16, 64);
    s += __shfl_xor(s, 32, 64);
    cbl[g] = nb2 * s;
  }

  // stage-load lane constants: thread t owns row (t>>2), fp32 cols [(t&3)*16..+16)
  const int srow = tid >> 2;
  const int scol = tid & 3;
  const int lofs = srow * LROW + scol * 16;

  float4 pf0, pf1, pf2, pf3;  // prefetched fp32 row slice
  bool   pvalid;

  auto stage_load = [&](int st) {
    const int grow = e0 + st * SROWS + srow;
    pvalid = grow < NE;
    pf0 = make_float4(0.f, 0.f, 0.f, 0.f);
    pf1 = pf0; pf2 = pf0; pf3 = pf0;
    if (pvalid) {
      const float* g = ex + (size_t)grow * KD + scol * 16;
      pf0 = *(const float4*)(g);
      pf1 = *(const float4*)(g + 4);
      pf2 = *(const float4*)(g + 8);
      pf3 = *(const float4*)(g + 12);
    }
  };

  auto stage_write = [&](int buf) {
    // norm: 16 squares + reduce across the 4 lanes sharing this row (scol)
    float sn = pf0.x*pf0.x + pf0.y*pf0.y + pf0.z*pf0.z + pf0.w*pf0.w
             + pf1.x*pf1.x + pf1.y*pf1.y + pf1.z*pf1.z + pf1.w*pf1.w
             + pf2.x*pf2.x + pf2.y*pf2.y + pf2.z*pf2.z + pf2.w*pf2.w
             + pf3.x*pf3.x + pf3.y*pf3.y + pf3.z*pf3.z + pf3.w*pf3.w;
    sn += __shfl_xor(sn, 1, 64);
    sn += __shfl_xor(sn, 2, 64);
    const half8 h0 = { (_Float16)pf0.x, (_Float16)pf0.y, (_Float16)pf0.z, (_Float16)pf0.w,
                       (_Float16)pf1.x, (_Float16)pf1.y, (_Float16)pf1.z, (_Float16)pf1.w };
    const half8 h1 = { (_Float16)pf2.x, (_Float16)pf2.y, (_Float16)pf2.z, (_Float16)pf2.w,
                       (_Float16)pf3.x, (_Float16)pf3.y, (_Float16)pf3.z, (_Float16)pf3.w };
    *(half8*)(&Ah[buf][lofs])     = h0;
    *(half8*)(&Ah[buf][lofs + 8]) = h1;
    if (scol == 0) Ce[buf][srow] = pvalid ? (nb2 * sn) : -1e30f;
  };

  // ---- prologue: stage 0 global -> regs -> LDS buf 0 ----
  stage_load(0);
  stage_write(0);
  __syncthreads();

  floatx4 acc[NGRP];
  #pragma unroll
  for (int g = 0; g < NGRP; ++g) acc[g] = floatx4{0.f, 0.f, 0.f, 0.f};

  for (int st = 0; st < NSTAGE; ++st) {
    const int b = st & 1;

    // prefetch next stage into registers (vmcnt chain, independent of ds_reads)
    if (st + 1 < NSTAGE) stage_load(st + 1);

    // compute 4 subtiles of 16 e-rows from LDS buf b
    #pragma unroll
    for (int sub = 0; sub < 4; ++sub) {
      const int abase = (sub * 16 + l15) * LROW + quad * 8;
      const half8 ae0 = *(const half8*)(&Ah[b][abase]);
      const half8 ae1 = *(const half8*)(&Ah[b][abase + 32]);
      const float4 ce4 = *(const float4*)(&Ce[b][sub * 16 + quad * 4]);
      const int4   lb4 = *(const int4*)(&Lb_all[st * SROWS + sub * 16 + quad * 4]);

      floatx4 d[NGRP];
      #pragma unroll
      for (int g = 0; g < NGRP; ++g) {
        floatx4 t = {0.f, 0.f, 0.f, 0.f};
        t = __builtin_amdgcn_mfma_f32_16x16x32_f16(ae0, bx[g][0], t, 0, 0, 0);
        t = __builtin_amdgcn_mfma_f32_16x16x32_f16(ae1, bx[g][1], t, 0, 0, 0);
        d[g] = t;
      }

      const float cef[4] = { ce4.x, ce4.y, ce4.z, ce4.w };
      float t[NGRP][4];
      #pragma unroll
      for (int g = 0; g < NGRP; ++g)
        #pragma unroll
        for (int r = 0; r < 4; ++r)
          t[g][r] = fminf(fmaf(s2, d[g][r], cbl[g] + cef[r]), 0.f);  // log2-domain

      // dead-subtile skip: t <= -25 => fp16(2^t) == 0 exactly (RTE), so the
      // MFMA2 contribution is a provable no-op. Wave-uniform branch.
      float m = -1e30f;
      #pragma unroll
      for (int g = 0; g < NGRP; ++g)
        m = fmaxf(m, fmaxf(fmaxf(t[g][0], t[g][1]), fmaxf(t[g][2], t[g][3])));
      if (__any(m > -25.f)) {
        half4v oh;
        oh[0] = (lb4.x == l15) ? (_Float16)1.f : (_Float16)0.f;
        oh[1] = (lb4.y == l15) ? (_Float16)1.f : (_Float16)0.f;
        oh[2] = (lb4.z == l15) ? (_Float16)1.f : (_Float16)0.f;
        oh[3] = (lb4.w == l15) ? (_Float16)1.f : (_Float16)0.f;

        #pragma unroll
        for (int g = 0; g < NGRP; ++g) {
          half4v p;
          #pragma unroll
          for (int r = 0; r < 4; ++r) p[r] = (_Float16)exp2_hw(t[g][r]);
          acc[g] = __builtin_amdgcn_mfma_f32_16x16x16f16(oh, p, acc[g], 0, 0, 0);
        }
      }
    }

    // single barrier per stage: writes go to buf b^1, whose last reads ended
    // before the barrier at the end of stage st-1; reads of buf b don't alias.
    if (st + 1 < NSTAGE) {
      stage_write((st + 1) & 1);
      __syncthreads();
    }
  }

  // Flush: acc[g] holds class_part[c = quad*4+r][b = l15] per col-group.
  // Private per-chunk slice, plain stores, zero contention.
  float* dst = part + (size_t)chunk * (NB * NC);
  #pragma unroll
  for (int r = 0; r < 4; ++r) {
    const int c = quad * 4 + r;
    if (c < NC) {
      #pragma unroll
      for (int g = 0; g < NGRP; ++g)
        dst[(bm0 + 64 * g + l15) * NC + c] = acc[g][r];
    }
  }
}

// ---------------------------------------------------------------------------
// reduce+finalize: out[bc] = log( sum_k part[k][bc] + eps ). Thread bc reads
// part[k][bc] -- consecutive threads hit consecutive addresses (coalesced);
// ~4 MB total, L2/L3-hot. Fixed summation order -> deterministic.
// ---------------------------------------------------------------------------
__global__ __launch_bounds__(256) void reduce_kernel(
    const float* __restrict__ part, float* __restrict__ out)
{
  const int bc = blockIdx.x * 256 + threadIdx.x;
  if (bc < NB * NC) {
    float s = 0.f;
    #pragma unroll 7
    for (int k = 0; k < NCHUNK; ++k) s += part[(size_t)k * (NB * NC) + bc];
    out[bc] = __logf(s + 1e-12f);
  }
}

extern "C" void kernel_launch(void* const* d_in, const int* in_sizes, int n_in,
                              void* d_out, int out_size, void* d_ws, size_t ws_size,
                              hipStream_t stream)
{
  const float* x        = (const float*)d_in[0];
  const float* ex       = (const float*)d_in[1];
  const int*   labels   = (const int*)d_in[2];
  const float* beta_raw = (const float*)d_in[3];
  float* out = (float*)d_out;

  // Workspace: only the contention-free partial array (98*10240*4 = 4,014,080 B)
  float* part = (float*)d_ws;

  dim3 g(NB / BCOLS, NCHUNK);
  main_kernel<<<g, 256, 0, stream>>>(x, ex, labels, beta_raw, part);
  reduce_kernel<<<40, 256, 0, stream>>>(part, out);
}